// Round 1
// baseline (1298.983 us; speedup 1.0000x reference)
//
#include <hip/hip_runtime.h>

#define DCH 64

__global__ void zero_f32(float* __restrict__ p, int n) {
    int i = blockIdx.x * blockDim.x + threadIdx.x;
    if (i < n) p[i] = 0.f;
}

__global__ void deg_count(const int* __restrict__ dst, float* __restrict__ deg, int E) {
    int e = blockIdx.x * blockDim.x + threadIdx.x;
    if (e < E) atomicAdd(&deg[dst[e]], 1.0f);
}

__global__ void finalize_dinv(float* __restrict__ deg, int n) {
    int i = blockIdx.x * blockDim.x + threadIdx.x;
    if (i < n) deg[i] = rsqrtf(deg[i] + 1.0f);   // +1 for self-loop; deg>=1 always
}

// H[n,64] = A[n,64] * W[64,64]; W staged in LDS, 4 rows per block-iteration.
__global__ void gemm64(const float* __restrict__ A, const float* __restrict__ W,
                       float* __restrict__ H, int nrows) {
    __shared__ float Wl[64 * 64];
    __shared__ float Al[4 * 64];
    for (int i = threadIdx.x; i < 64 * 64; i += blockDim.x) Wl[i] = W[i];
    const int c  = threadIdx.x & 63;
    const int rl = threadIdx.x >> 6;          // 0..3
    const int ngroups = (nrows + 3) >> 2;
    for (int g = blockIdx.x; g < ngroups; g += gridDim.x) {
        const int rowbase = g * 4;
        __syncthreads();                      // protect Al reuse (and first-iter Wl)
        const int idx = rowbase * 64 + (int)threadIdx.x;
        Al[threadIdx.x] = (idx < nrows * 64) ? A[idx] : 0.f;
        __syncthreads();
        const int row = rowbase + rl;
        if (row < nrows) {
            float sum = 0.f;
            #pragma unroll
            for (int k = 0; k < 64; ++k)
                sum += Al[rl * 64 + k] * Wl[k * 64 + c];
            H[row * 64 + c] = sum;
        }
    }
}

// out[i][c] = h[i][c] * dinv[i]^2   (self-loop term; fully overwrites out)
__global__ void init_self(const float* __restrict__ h, const float* __restrict__ dinv,
                          float* __restrict__ out, int n) {
    int i = blockIdx.x * blockDim.x + threadIdx.x;
    if (i < n * DCH) {
        int r = i >> 6;
        float di = dinv[r];
        out[i] = h[i] * di * di;
    }
}

// one thread per (edge, channel): out[dst][c] += h[src][c] * dinv[src]*dinv[dst]
__global__ void edge_scatter(const float* __restrict__ h, const int* __restrict__ src,
                             const int* __restrict__ dst, const float* __restrict__ dinv,
                             float* __restrict__ out, int E) {
    const int total = E * DCH;                // 102.4M < 2^31
    for (int idx = blockIdx.x * blockDim.x + threadIdx.x; idx < total;
         idx += gridDim.x * blockDim.x) {
        int e = idx >> 6;
        int c = idx & 63;
        int s = src[e];
        int d = dst[e];
        float v = h[s * DCH + c] * (dinv[s] * dinv[d]);
        atomicAdd(&out[d * DCH + c], v);
    }
}

__global__ void bias_act(float* __restrict__ io, const float* __restrict__ b,
                         int n, int do_relu) {
    int i = blockIdx.x * blockDim.x + threadIdx.x;
    if (i < n * DCH) {
        float v = io[i] + b[i & 63];
        io[i] = do_relu ? fmaxf(v, 0.f) : v;
    }
}

extern "C" void kernel_launch(void* const* d_in, const int* in_sizes, int n_in,
                              void* d_out, int out_size, void* d_ws, size_t ws_size,
                              hipStream_t stream) {
    const float* x  = (const float*)d_in[0];
    const int*   ei = (const int*)d_in[1];
    const float* W1 = (const float*)d_in[2];
    const float* b1 = (const float*)d_in[3];
    const float* W2 = (const float*)d_in[4];
    const float* b2 = (const float*)d_in[5];
    const float* W3 = (const float*)d_in[6];
    const float* b3 = (const float*)d_in[7];

    const int N = in_sizes[0] / DCH;
    const int E = in_sizes[1] / 2;
    const int* src = ei;
    const int* dst = ei + E;

    char* ws = (char*)d_ws;
    size_t off = 0;
    float* dinv = (float*)(ws + off); off += ((size_t)N * 4 + 255) / 256 * 256;
    float* hbuf = (float*)(ws + off); off += (size_t)N * DCH * 4;
    float* agg  = (float*)(ws + off); off += (size_t)N * DCH * 4;
    float* out  = (float*)d_out;

    const int T = 256;
    const int gN   = (N + T - 1) / T;
    const int gE   = (E + T - 1) / T;
    const int gND  = (N * DCH + T - 1) / T;
    const int gSC  = 16384;                    // grid-stride scatter
    const int gGM  = 2048;                     // grid-stride gemm

    // degree -> dinv
    zero_f32<<<gN, T, 0, stream>>>(dinv, N);
    deg_count<<<gE, T, 0, stream>>>(dst, dinv, E);
    finalize_dinv<<<gN, T, 0, stream>>>(dinv, N);

    // layer 1: x -> agg
    gemm64<<<gGM, T, 0, stream>>>(x, W1, hbuf, N);
    init_self<<<gND, T, 0, stream>>>(hbuf, dinv, agg, N);
    edge_scatter<<<gSC, T, 0, stream>>>(hbuf, src, dst, dinv, agg, E);
    bias_act<<<gND, T, 0, stream>>>(agg, b1, N, 1);

    // layer 2: agg -> agg (hbuf intermediate)
    gemm64<<<gGM, T, 0, stream>>>(agg, W2, hbuf, N);
    init_self<<<gND, T, 0, stream>>>(hbuf, dinv, agg, N);
    edge_scatter<<<gSC, T, 0, stream>>>(hbuf, src, dst, dinv, agg, E);
    bias_act<<<gND, T, 0, stream>>>(agg, b2, N, 1);

    // layer 3: agg -> d_out
    gemm64<<<gGM, T, 0, stream>>>(agg, W3, hbuf, N);
    init_self<<<gND, T, 0, stream>>>(hbuf, dinv, out, N);
    edge_scatter<<<gSC, T, 0, stream>>>(hbuf, src, dst, dinv, out, E);
    bias_act<<<gND, T, 0, stream>>>(out, b3, N, 0);
}

// Round 3
// 549.654 us; speedup vs baseline: 2.3633x; 2.3633x over previous
//
#include <hip/hip_runtime.h>

#define DCH 64
#define SCAN_T 256

__global__ void zero_i32(int* __restrict__ p, int n) {
    int i = blockIdx.x * blockDim.x + threadIdx.x;
    if (i < n) p[i] = 0;
}

__global__ void deg_count(const int* __restrict__ dst, int* __restrict__ deg, int E) {
    int e = blockIdx.x * blockDim.x + threadIdx.x;
    if (e < E) atomicAdd(&deg[dst[e]], 1);
}

__global__ void make_dinv(const int* __restrict__ deg, float* __restrict__ dinv, int n) {
    int i = blockIdx.x * blockDim.x + threadIdx.x;
    if (i < n) dinv[i] = rsqrtf((float)deg[i] + 1.0f);   // +1 self-loop
}

// --- exclusive scan of deg[0..n) into rowptr[0..n], rowptr[n]=E ---
__global__ void scan1(const int* __restrict__ deg, int* __restrict__ rowptr,
                      int* __restrict__ bsum, int n) {
    __shared__ int lds[SCAN_T];
    int t = threadIdx.x;
    int i = blockIdx.x * SCAN_T + t;
    int v = (i < n) ? deg[i] : 0;
    lds[t] = v;
    __syncthreads();
    for (int off = 1; off < SCAN_T; off <<= 1) {
        int add = (t >= off) ? lds[t - off] : 0;
        __syncthreads();
        lds[t] += add;
        __syncthreads();
    }
    if (i < n) rowptr[i] = lds[t] - v;                   // exclusive within block
    if (t == SCAN_T - 1) bsum[blockIdx.x] = lds[t];
}

__global__ void scan2(const int* __restrict__ bsum, int* __restrict__ boff, int nb) {
    __shared__ int lds[1024];
    int t = threadIdx.x;
    int v = (t < nb) ? bsum[t] : 0;
    lds[t] = v;
    __syncthreads();
    for (int off = 1; off < 1024; off <<= 1) {
        int add = (t >= off) ? lds[t - off] : 0;
        __syncthreads();
        lds[t] += add;
        __syncthreads();
    }
    if (t < nb) boff[t] = lds[t] - v;                    // exclusive over blocks
}

__global__ void scan3(int* __restrict__ rowptr, const int* __restrict__ boff,
                      int n, int E) {
    int i = blockIdx.x * blockDim.x + threadIdx.x;
    if (i < n) rowptr[i] += boff[i / SCAN_T];
    if (i == 0) rowptr[n] = E;
}

__global__ void copy_i32(const int* __restrict__ a, int* __restrict__ b, int n) {
    int i = blockIdx.x * blockDim.x + threadIdx.x;
    if (i < n) b[i] = a[i];
}

__global__ void csr_fill(const int* __restrict__ src, const int* __restrict__ dst,
                         int* __restrict__ cursor, int* __restrict__ srcs, int E) {
    int e = blockIdx.x * blockDim.x + threadIdx.x;
    if (e < E) {
        int d = dst[e];
        int p = atomicAdd(&cursor[d], 1);
        srcs[p] = src[e];
    }
}

// H[n,64] = A[n,64] * W[64,64]; W staged in LDS, 4 rows per block-iteration.
__global__ void gemm64(const float* __restrict__ A, const float* __restrict__ W,
                       float* __restrict__ H, int nrows) {
    __shared__ float Wl[64 * 64];
    __shared__ float Al[4 * 64];
    for (int i = threadIdx.x; i < 64 * 64; i += blockDim.x) Wl[i] = W[i];
    const int c  = threadIdx.x & 63;
    const int rl = threadIdx.x >> 6;
    const int ngroups = (nrows + 3) >> 2;
    for (int g = blockIdx.x; g < ngroups; g += gridDim.x) {
        const int rowbase = g * 4;
        __syncthreads();
        const int idx = rowbase * 64 + (int)threadIdx.x;
        Al[threadIdx.x] = (idx < nrows * 64) ? A[idx] : 0.f;
        __syncthreads();
        const int row = rowbase + rl;
        if (row < nrows) {
            float sum = 0.f;
            #pragma unroll
            for (int k = 0; k < 64; ++k)
                sum += Al[rl * 64 + k] * Wl[k * 64 + c];
            H[row * 64 + c] = sum;
        }
    }
}

// One wave per dst node; lane = channel. Fuses self-loop + norm + bias + ReLU.
// out[d][c] = act( (h[d][c]*dinv[d] + sum_e h[src_e][c]*dinv[src_e]) * dinv[d] + b[c] )
__global__ __launch_bounds__(256) void aggregate(
    const float* __restrict__ h, const int* __restrict__ rowptr,
    const int* __restrict__ srcs, const float* __restrict__ dinv,
    const float* __restrict__ b, float* __restrict__ out, int n, int do_relu)
{
    int wid  = (blockIdx.x * blockDim.x + threadIdx.x) >> 6;
    int lane = threadIdx.x & 63;
    if (wid >= n) return;
    int beg = rowptr[wid], end = rowptr[wid + 1];
    float dd  = dinv[wid];
    float acc = h[(size_t)wid * DCH + lane] * dd;        // self-loop term
    int e = beg;
    for (; e + 4 <= end; e += 4) {
        int s0 = srcs[e + 0], s1 = srcs[e + 1], s2 = srcs[e + 2], s3 = srcs[e + 3];
        float w0 = dinv[s0], w1 = dinv[s1], w2 = dinv[s2], w3 = dinv[s3];
        float h0 = h[(size_t)s0 * DCH + lane];
        float h1 = h[(size_t)s1 * DCH + lane];
        float h2 = h[(size_t)s2 * DCH + lane];
        float h3 = h[(size_t)s3 * DCH + lane];
        acc += h0 * w0 + h1 * w1 + h2 * w2 + h3 * w3;
    }
    for (; e < end; ++e) {
        int s = srcs[e];
        acc += h[(size_t)s * DCH + lane] * dinv[s];
    }
    float v = acc * dd + b[lane];
    out[(size_t)wid * DCH + lane] = do_relu ? fmaxf(v, 0.f) : v;
}

extern "C" void kernel_launch(void* const* d_in, const int* in_sizes, int n_in,
                              void* d_out, int out_size, void* d_ws, size_t ws_size,
                              hipStream_t stream) {
    const float* x  = (const float*)d_in[0];
    const int*   ei = (const int*)d_in[1];
    const float* W1 = (const float*)d_in[2];
    const float* b1 = (const float*)d_in[3];
    const float* W2 = (const float*)d_in[4];
    const float* b2 = (const float*)d_in[5];
    const float* W3 = (const float*)d_in[6];
    const float* b3 = (const float*)d_in[7];

    const int N = in_sizes[0] / DCH;
    const int E = in_sizes[1] / 2;
    const int* src = ei;
    const int* dst = ei + E;

    char* ws = (char*)d_ws;
    size_t off = 0;
    auto alloc = [&](size_t bytes) { void* p = ws + off; off = (off + bytes + 255) & ~(size_t)255; return p; };
    int*   deg    = (int*)  alloc((size_t)N * 4);
    int*   rowptr = (int*)  alloc(((size_t)N + 1) * 4);
    int*   cursor = (int*)  alloc((size_t)N * 4);
    int*   bsum   = (int*)  alloc(1024 * 4);
    int*   boff   = (int*)  alloc(1024 * 4);
    int*   srcs   = (int*)  alloc((size_t)E * 4);
    float* dinv   = (float*)alloc((size_t)N * 4);
    float* hbuf   = (float*)alloc((size_t)N * DCH * 4);
    float* agg    = (float*)alloc((size_t)N * DCH * 4);
    float* out    = (float*)d_out;

    const int T = 256;
    const int gN  = (N + T - 1) / T;
    const int gN1 = (N + 1 + T - 1) / T;
    const int gE  = (E + T - 1) / T;
    const int nb  = (N + SCAN_T - 1) / SCAN_T;     // 391 <= 1024
    const int gAG = (N * DCH + T - 1) / T;         // one 64-lane wave per node
    const int gGM = 2048;

    // ---- degree + dinv + CSR ----
    zero_i32<<<gN, T, 0, stream>>>(deg, N);
    deg_count<<<gE, T, 0, stream>>>(dst, deg, E);
    make_dinv<<<gN, T, 0, stream>>>(deg, dinv, N);
    scan1<<<nb, SCAN_T, 0, stream>>>(deg, rowptr, bsum, N);
    scan2<<<1, 1024, 0, stream>>>(bsum, boff, nb);
    scan3<<<gN1, T, 0, stream>>>(rowptr, boff, N, E);
    copy_i32<<<gN, T, 0, stream>>>(rowptr, cursor, N);
    csr_fill<<<gE, T, 0, stream>>>(src, dst, cursor, srcs, E);

    // ---- layer 1: x -> agg ----
    gemm64<<<gGM, T, 0, stream>>>(x, W1, hbuf, N);
    aggregate<<<gAG, T, 0, stream>>>(hbuf, rowptr, srcs, dinv, b1, agg, N, 1);

    // ---- layer 2: agg -> agg ----
    gemm64<<<gGM, T, 0, stream>>>(agg, W2, hbuf, N);
    aggregate<<<gAG, T, 0, stream>>>(hbuf, rowptr, srcs, dinv, b2, agg, N, 1);

    // ---- layer 3: agg -> d_out ----
    gemm64<<<gGM, T, 0, stream>>>(agg, W3, hbuf, N);
    aggregate<<<gAG, T, 0, stream>>>(hbuf, rowptr, srcs, dinv, b3, out, N, 0);
}

// Round 4
// 410.432 us; speedup vs baseline: 3.1649x; 1.3392x over previous
//
#include <hip/hip_runtime.h>

#define DCH 64
#define NBSHIFT 8
#define BROWS 256            // nodes per bucket = 1<<NBSHIFT
#define MAXNB 512
#define CAP 8192             // pass-C staging capacity (edges per bucket)
#define CHUNK 4096           // pass-B edges per block

__global__ void zero_i32(int* __restrict__ p, int n) {
    int i = blockIdx.x * blockDim.x + threadIdx.x;
    if (i < n) p[i] = 0;
}

// pass A: global bucket histogram via per-block LDS histograms
__global__ __launch_bounds__(256) void bucket_hist(const int* __restrict__ dst,
                                                   int* __restrict__ counts, int E, int NB) {
    __shared__ int hist[MAXNB];
    for (int i = threadIdx.x; i < NB; i += blockDim.x) hist[i] = 0;
    __syncthreads();
    for (int e = blockIdx.x * blockDim.x + threadIdx.x; e < E; e += gridDim.x * blockDim.x)
        atomicAdd(&hist[dst[e] >> NBSHIFT], 1);
    __syncthreads();
    for (int i = threadIdx.x; i < NB; i += blockDim.x) {
        int c = hist[i];
        if (c) atomicAdd(&counts[i], c);
    }
}

// scan bucket counts -> bases, init global cursors; also rowptr[N]=E
__global__ __launch_bounds__(MAXNB) void bucket_scan(const int* __restrict__ counts,
        int* __restrict__ bases, int* __restrict__ cursor, int* __restrict__ rowptr,
        int NB, int N, int E) {
    __shared__ int lds[MAXNB];
    int t = threadIdx.x;
    int v = (t < NB) ? counts[t] : 0;
    lds[t] = v;
    __syncthreads();
    for (int off = 1; off < MAXNB; off <<= 1) {
        int add = (t >= off) ? lds[t - off] : 0;
        __syncthreads();
        lds[t] += add;
        __syncthreads();
    }
    if (t < NB) { int b = lds[t] - v; bases[t] = b; cursor[t] = b; }
    if (t == 0) rowptr[N] = E;
}

// pass B: scatter edges into bucket-contiguous regions as packed (dstLow8<<24)|src
__global__ __launch_bounds__(256) void bucket_scatter(const int* __restrict__ src,
        const int* __restrict__ dst, int* __restrict__ cursor,
        unsigned int* __restrict__ tmp, int E, int NB) {
    __shared__ int hist[MAXNB];
    __shared__ int res[MAXNB];
    const int base_e = blockIdx.x * CHUNK;
    const int nloc = min(CHUNK, E - base_e);
    for (int i = threadIdx.x; i < NB; i += blockDim.x) hist[i] = 0;
    __syncthreads();
    for (int i = threadIdx.x; i < nloc; i += blockDim.x)
        atomicAdd(&hist[dst[base_e + i] >> NBSHIFT], 1);
    __syncthreads();
    for (int i = threadIdx.x; i < NB; i += blockDim.x) {
        int c = hist[i];
        res[i] = c ? atomicAdd(&cursor[i], c) : 0;
        hist[i] = 0;                       // reuse as local cursor
    }
    __syncthreads();
    for (int i = threadIdx.x; i < nloc; i += blockDim.x) {
        int d = dst[base_e + i];
        int b = d >> NBSHIFT;
        int r = atomicAdd(&hist[b], 1);
        unsigned int packed = ((unsigned int)(d & (BROWS - 1)) << 24) |
                              (unsigned int)src[base_e + i];
        tmp[res[b] + r] = packed;
    }
}

// pass C: one block per bucket -> rowptr, dinv, coalesced srcs
__global__ __launch_bounds__(BROWS) void bucket_to_csr(
        const unsigned int* __restrict__ tmp, const int* __restrict__ bases,
        const int* __restrict__ counts, int* __restrict__ rowptr,
        int* __restrict__ srcs, float* __restrict__ dinv, int N) {
    __shared__ int hist[BROWS];
    __shared__ int off[BROWS];
    __shared__ int cur[BROWS];
    __shared__ int stage[CAP];
    const int b = blockIdx.x;
    const int base = bases[b], count = counts[b];
    const int t = threadIdx.x;
    hist[t] = 0;
    __syncthreads();
    for (int i = t; i < count; i += BROWS)
        atomicAdd(&hist[tmp[base + i] >> 24], 1);
    __syncthreads();
    int v = hist[t];
    off[t] = v;
    __syncthreads();
    for (int o = 1; o < BROWS; o <<= 1) {
        int add = (t >= o) ? off[t - o] : 0;
        __syncthreads();
        off[t] += add;
        __syncthreads();
    }
    int excl = off[t] - v;
    cur[t] = excl;
    int node = (b << NBSHIFT) + t;
    if (node <= N) rowptr[node] = base + excl;     // node==N lands in last bucket -> rowptr[N]=E
    if (node < N)  dinv[node] = rsqrtf((float)v + 1.0f);
    __syncthreads();
    const bool st = (count <= CAP);
    for (int i = t; i < count; i += BROWS) {
        unsigned int p = tmp[base + i];
        int low = p >> 24;
        int s = (int)(p & 0xFFFFFFu);
        int pos = atomicAdd(&cur[low], 1);
        if (st) stage[pos] = s;
        else    srcs[base + pos] = s;              // overflow fallback (uncoalesced, rare)
    }
    __syncthreads();
    if (st)
        for (int i = t; i < count; i += BROWS) srcs[base + i] = stage[i];
}

// register-tiled H[r][c] = (A[64xK] * W[KxC]) * dinv[r]; 64x64 tile, 4x4 per thread
__global__ __launch_bounds__(256) void gemm64(const float* __restrict__ A,
        const float* __restrict__ W, const float* __restrict__ dinv,
        float* __restrict__ H, int nrows) {
    __shared__ float Wl[64 * 64];      // [k][c]
    __shared__ float Al[64 * 65];      // [r][k], pad 65
    for (int i = threadIdx.x; i < 1024; i += 256) {
        float4 w = ((const float4*)W)[i];
        int k = i >> 4, c = (i & 15) * 4;
        float* p = &Wl[k * 64 + c];
        p[0] = w.x; p[1] = w.y; p[2] = w.z; p[3] = w.w;
    }
    const int tx = threadIdx.x & 15;
    const int ty = threadIdx.x >> 4;
    const int c0 = tx * 4, r0 = ty * 4;
    const int ntiles = (nrows + 63) >> 6;
    for (int tile = blockIdx.x; tile < ntiles; tile += gridDim.x) {
        const int rowbase = tile << 6;
        const int rmax = min(64, nrows - rowbase);
        __syncthreads();
        for (int i = threadIdx.x; i < 1024; i += 256) {
            int r = i >> 4, k = (i & 15) * 4;
            float4 a = (r < rmax) ? *(const float4*)(A + (size_t)(rowbase + r) * 64 + k)
                                  : make_float4(0.f, 0.f, 0.f, 0.f);
            float* p = &Al[r * 65 + k];
            p[0] = a.x; p[1] = a.y; p[2] = a.z; p[3] = a.w;
        }
        __syncthreads();
        float acc[4][4] = {};
        #pragma unroll
        for (int k = 0; k < 64; ++k) {
            float4 wv = *(const float4*)&Wl[k * 64 + c0];
            float a0 = Al[(r0 + 0) * 65 + k];
            float a1 = Al[(r0 + 1) * 65 + k];
            float a2 = Al[(r0 + 2) * 65 + k];
            float a3 = Al[(r0 + 3) * 65 + k];
            acc[0][0] += a0 * wv.x; acc[0][1] += a0 * wv.y; acc[0][2] += a0 * wv.z; acc[0][3] += a0 * wv.w;
            acc[1][0] += a1 * wv.x; acc[1][1] += a1 * wv.y; acc[1][2] += a1 * wv.z; acc[1][3] += a1 * wv.w;
            acc[2][0] += a2 * wv.x; acc[2][1] += a2 * wv.y; acc[2][2] += a2 * wv.z; acc[2][3] += a2 * wv.w;
            acc[3][0] += a3 * wv.x; acc[3][1] += a3 * wv.y; acc[3][2] += a3 * wv.z; acc[3][3] += a3 * wv.w;
        }
        #pragma unroll
        for (int i = 0; i < 4; ++i) {
            int r = r0 + i;
            if (r < rmax) {
                float s = dinv[rowbase + r];
                float4 o = make_float4(acc[i][0] * s, acc[i][1] * s, acc[i][2] * s, acc[i][3] * s);
                *(float4*)(H + (size_t)(rowbase + r) * 64 + c0) = o;
            }
        }
    }
}

// one wave per dst node; lane = channel. hs rows are pre-scaled by dinv[src].
// out[d][c] = act( (sum_{s in N(d) ∪ {d}} hs[s][c]) * dinv[d] + b[c] )
__global__ __launch_bounds__(256) void aggregate(
    const float* __restrict__ hs, const int* __restrict__ rowptr,
    const int* __restrict__ srcs, const float* __restrict__ dinv,
    const float* __restrict__ b, float* __restrict__ out, int n, int do_relu)
{
    int wid  = (blockIdx.x * blockDim.x + threadIdx.x) >> 6;
    int lane = threadIdx.x & 63;
    if (wid >= n) return;
    int beg = rowptr[wid], end = rowptr[wid + 1];
    float acc = hs[(size_t)wid * DCH + lane];          // self-loop term (pre-scaled)
    int e = beg;
    for (; e + 4 <= end; e += 4) {
        int s0 = srcs[e], s1 = srcs[e + 1], s2 = srcs[e + 2], s3 = srcs[e + 3];
        acc += hs[(size_t)s0 * DCH + lane] + hs[(size_t)s1 * DCH + lane]
             + hs[(size_t)s2 * DCH + lane] + hs[(size_t)s3 * DCH + lane];
    }
    for (; e < end; ++e) acc += hs[(size_t)srcs[e] * DCH + lane];
    float v = acc * dinv[wid] + b[lane];
    out[(size_t)wid * DCH + lane] = do_relu ? fmaxf(v, 0.f) : v;
}

extern "C" void kernel_launch(void* const* d_in, const int* in_sizes, int n_in,
                              void* d_out, int out_size, void* d_ws, size_t ws_size,
                              hipStream_t stream) {
    const float* x  = (const float*)d_in[0];
    const int*   ei = (const int*)d_in[1];
    const float* W1 = (const float*)d_in[2];
    const float* b1 = (const float*)d_in[3];
    const float* W2 = (const float*)d_in[4];
    const float* b2 = (const float*)d_in[5];
    const float* W3 = (const float*)d_in[6];
    const float* b3 = (const float*)d_in[7];

    const int N = in_sizes[0] / DCH;
    const int E = in_sizes[1] / 2;
    const int* src = ei;
    const int* dst = ei + E;
    const int NB = (N + BROWS - 1) >> NBSHIFT;     // 391

    char* ws = (char*)d_ws;
    size_t off = 0;
    auto alloc = [&](size_t bytes) { void* p = ws + off; off = (off + bytes + 255) & ~(size_t)255; return p; };
    int*   counts = (int*)  alloc((size_t)MAXNB * 4);
    int*   bases  = (int*)  alloc((size_t)MAXNB * 4);
    int*   cursor = (int*)  alloc((size_t)MAXNB * 4);
    int*   rowptr = (int*)  alloc(((size_t)N + 1) * 4);
    int*   srcs   = (int*)  alloc((size_t)E * 4);
    float* dinv   = (float*)alloc((size_t)N * 4);
    float* hbuf   = (float*)alloc((size_t)N * DCH * 4);
    float* agg    = (float*)alloc((size_t)N * DCH * 4);
    unsigned int* tmp = (unsigned int*)hbuf;       // alias: tmp dead before first gemm writes hbuf
    float* out = (float*)d_out;

    const int T = 256;
    const int gAG  = (N * DCH + T - 1) / T;        // one 64-lane wave per node
    const int gGM  = (N + 63) / 64;                // one block per 64-row tile
    const int nchk = (E + CHUNK - 1) / CHUNK;

    // ---- CSR build (counting sort by dst) ----
    zero_i32<<<(NB + T - 1) / T, T, 0, stream>>>(counts, NB);
    bucket_hist<<<256, T, 0, stream>>>(dst, counts, E, NB);
    bucket_scan<<<1, MAXNB, 0, stream>>>(counts, bases, cursor, rowptr, NB, N, E);
    bucket_scatter<<<nchk, T, 0, stream>>>(src, dst, cursor, tmp, E, NB);
    bucket_to_csr<<<NB, BROWS, 0, stream>>>(tmp, bases, counts, rowptr, srcs, dinv, N);

    // ---- layer 1: x -> agg ----
    gemm64<<<gGM, T, 0, stream>>>(x, W1, dinv, hbuf, N);
    aggregate<<<gAG, T, 0, stream>>>(hbuf, rowptr, srcs, dinv, b1, agg, N, 1);

    // ---- layer 2: agg -> agg ----
    gemm64<<<gGM, T, 0, stream>>>(agg, W2, dinv, hbuf, N);
    aggregate<<<gAG, T, 0, stream>>>(hbuf, rowptr, srcs, dinv, b2, agg, N, 1);

    // ---- layer 3: agg -> d_out ----
    gemm64<<<gGM, T, 0, stream>>>(agg, W3, dinv, hbuf, N);
    aggregate<<<gAG, T, 0, stream>>>(hbuf, rowptr, srcs, dinv, b3, out, N, 0);
}

// Round 5
// 344.613 us; speedup vs baseline: 3.7694x; 1.1910x over previous
//
#include <hip/hip_runtime.h>
#include <hip/hip_fp16.h>

#define DCH 64
#define NBSHIFT 8
#define BROWS 256            // nodes per bucket = 1<<NBSHIFT
#define MAXNB 512
#define CAP 8192             // pass-C staging capacity (edges per bucket)
#define CHUNK 4096           // pass-B edges per block

__global__ void zero_i32(int* __restrict__ p, int n) {
    int i = blockIdx.x * blockDim.x + threadIdx.x;
    if (i < n) p[i] = 0;
}

// pass A: global bucket histogram via per-block LDS histograms
__global__ __launch_bounds__(256) void bucket_hist(const int* __restrict__ dst,
                                                   int* __restrict__ counts, int E, int NB) {
    __shared__ int hist[MAXNB];
    for (int i = threadIdx.x; i < NB; i += blockDim.x) hist[i] = 0;
    __syncthreads();
    for (int e = blockIdx.x * blockDim.x + threadIdx.x; e < E; e += gridDim.x * blockDim.x)
        atomicAdd(&hist[dst[e] >> NBSHIFT], 1);
    __syncthreads();
    for (int i = threadIdx.x; i < NB; i += blockDim.x) {
        int c = hist[i];
        if (c) atomicAdd(&counts[i], c);
    }
}

// scan bucket counts -> bases, init global cursors; also rowptr[N]=E
__global__ __launch_bounds__(MAXNB) void bucket_scan(const int* __restrict__ counts,
        int* __restrict__ bases, int* __restrict__ cursor, int* __restrict__ rowptr,
        int NB, int N, int E) {
    __shared__ int lds[MAXNB];
    int t = threadIdx.x;
    int v = (t < NB) ? counts[t] : 0;
    lds[t] = v;
    __syncthreads();
    for (int off = 1; off < MAXNB; off <<= 1) {
        int add = (t >= off) ? lds[t - off] : 0;
        __syncthreads();
        lds[t] += add;
        __syncthreads();
    }
    if (t < NB) { int b = lds[t] - v; bases[t] = b; cursor[t] = b; }
    if (t == 0) rowptr[N] = E;
}

// pass B: scatter edges into bucket-contiguous regions as packed (dstLow8<<24)|src
__global__ __launch_bounds__(256) void bucket_scatter(const int* __restrict__ src,
        const int* __restrict__ dst, int* __restrict__ cursor,
        unsigned int* __restrict__ tmp, int E, int NB) {
    __shared__ int hist[MAXNB];
    __shared__ int res[MAXNB];
    const int base_e = blockIdx.x * CHUNK;
    const int nloc = min(CHUNK, E - base_e);
    for (int i = threadIdx.x; i < NB; i += blockDim.x) hist[i] = 0;
    __syncthreads();
    for (int i = threadIdx.x; i < nloc; i += blockDim.x)
        atomicAdd(&hist[dst[base_e + i] >> NBSHIFT], 1);
    __syncthreads();
    for (int i = threadIdx.x; i < NB; i += blockDim.x) {
        int c = hist[i];
        res[i] = c ? atomicAdd(&cursor[i], c) : 0;
        hist[i] = 0;                       // reuse as local cursor
    }
    __syncthreads();
    for (int i = threadIdx.x; i < nloc; i += blockDim.x) {
        int d = dst[base_e + i];
        int b = d >> NBSHIFT;
        int r = atomicAdd(&hist[b], 1);
        unsigned int packed = ((unsigned int)(d & (BROWS - 1)) << 24) |
                              (unsigned int)src[base_e + i];
        tmp[res[b] + r] = packed;
    }
}

// pass C: one block per bucket -> rowptr, dinv, coalesced srcs
__global__ __launch_bounds__(BROWS) void bucket_to_csr(
        const unsigned int* __restrict__ tmp, const int* __restrict__ bases,
        const int* __restrict__ counts, int* __restrict__ rowptr,
        int* __restrict__ srcs, float* __restrict__ dinv, int N) {
    __shared__ int hist[BROWS];
    __shared__ int off[BROWS];
    __shared__ int cur[BROWS];
    __shared__ int stage[CAP];
    const int b = blockIdx.x;
    const int base = bases[b], count = counts[b];
    const int t = threadIdx.x;
    hist[t] = 0;
    __syncthreads();
    for (int i = t; i < count; i += BROWS)
        atomicAdd(&hist[tmp[base + i] >> 24], 1);
    __syncthreads();
    int v = hist[t];
    off[t] = v;
    __syncthreads();
    for (int o = 1; o < BROWS; o <<= 1) {
        int add = (t >= o) ? off[t - o] : 0;
        __syncthreads();
        off[t] += add;
        __syncthreads();
    }
    int excl = off[t] - v;
    cur[t] = excl;
    int node = (b << NBSHIFT) + t;
    if (node <= N) rowptr[node] = base + excl;     // node==N lands in last bucket -> rowptr[N]=E
    if (node < N)  dinv[node] = rsqrtf((float)v + 1.0f);
    __syncthreads();
    const bool st = (count <= CAP);
    for (int i = t; i < count; i += BROWS) {
        unsigned int p = tmp[base + i];
        int low = p >> 24;
        int s = (int)(p & 0xFFFFFFu);
        int pos = atomicAdd(&cur[low], 1);
        if (st) stage[pos] = s;
        else    srcs[base + pos] = s;              // overflow fallback (uncoalesced, rare)
    }
    __syncthreads();
    if (st)
        for (int i = t; i < count; i += BROWS) srcs[base + i] = stage[i];
}

// register-tiled Hs[r][c] = half( (A[64xK] * W[KxC]) * dinv[r] ); 64x64 tile, 4x4/thread
__global__ __launch_bounds__(256) void gemm64(const float* __restrict__ A,
        const float* __restrict__ W, const float* __restrict__ dinv,
        __half* __restrict__ H, int nrows) {
    __shared__ float Wl[64 * 64];      // [k][c]
    __shared__ float Al[64 * 65];      // [r][k], pad 65
    for (int i = threadIdx.x; i < 1024; i += 256) {
        float4 w = ((const float4*)W)[i];
        int k = i >> 4, c = (i & 15) * 4;
        float* p = &Wl[k * 64 + c];
        p[0] = w.x; p[1] = w.y; p[2] = w.z; p[3] = w.w;
    }
    const int tx = threadIdx.x & 15;
    const int ty = threadIdx.x >> 4;
    const int c0 = tx * 4, r0 = ty * 4;
    const int ntiles = (nrows + 63) >> 6;
    for (int tile = blockIdx.x; tile < ntiles; tile += gridDim.x) {
        const int rowbase = tile << 6;
        const int rmax = min(64, nrows - rowbase);
        __syncthreads();
        for (int i = threadIdx.x; i < 1024; i += 256) {
            int r = i >> 4, k = (i & 15) * 4;
            float4 a = (r < rmax) ? *(const float4*)(A + (size_t)(rowbase + r) * 64 + k)
                                  : make_float4(0.f, 0.f, 0.f, 0.f);
            float* p = &Al[r * 65 + k];
            p[0] = a.x; p[1] = a.y; p[2] = a.z; p[3] = a.w;
        }
        __syncthreads();
        float acc[4][4] = {};
        #pragma unroll
        for (int k = 0; k < 64; ++k) {
            float4 wv = *(const float4*)&Wl[k * 64 + c0];
            float a0 = Al[(r0 + 0) * 65 + k];
            float a1 = Al[(r0 + 1) * 65 + k];
            float a2 = Al[(r0 + 2) * 65 + k];
            float a3 = Al[(r0 + 3) * 65 + k];
            acc[0][0] += a0 * wv.x; acc[0][1] += a0 * wv.y; acc[0][2] += a0 * wv.z; acc[0][3] += a0 * wv.w;
            acc[1][0] += a1 * wv.x; acc[1][1] += a1 * wv.y; acc[1][2] += a1 * wv.z; acc[1][3] += a1 * wv.w;
            acc[2][0] += a2 * wv.x; acc[2][1] += a2 * wv.y; acc[2][2] += a2 * wv.z; acc[2][3] += a2 * wv.w;
            acc[3][0] += a3 * wv.x; acc[3][1] += a3 * wv.y; acc[3][2] += a3 * wv.z; acc[3][3] += a3 * wv.w;
        }
        #pragma unroll
        for (int i = 0; i < 4; ++i) {
            int r = r0 + i;
            if (r < rmax) {
                float s = dinv[rowbase + r];
                __half2* ph = (__half2*)(H + (size_t)(rowbase + r) * 64 + c0);
                ph[0] = __floats2half2_rn(acc[i][0] * s, acc[i][1] * s);
                ph[1] = __floats2half2_rn(acc[i][2] * s, acc[i][3] * s);
            }
        }
    }
}

__device__ __forceinline__ void acc_row(float acc[8], const __half* __restrict__ hs,
                                        int s, int q) {
    const float4 v = *(const float4*)((const char*)hs + ((size_t)s << 7) + (q << 4));
    const __half2* hp = (const __half2*)&v;
    #pragma unroll
    for (int j = 0; j < 4; ++j) {
        float2 f = __half22float2(hp[j]);
        acc[2 * j]     += f.x;
        acc[2 * j + 1] += f.y;
    }
}

// one wave per dst node. lane = g*8+q: g = edge subgroup (8 edges in flight),
// q = channel oct (half8 = 16B). hs rows pre-scaled by dinv[src], fp16.
// out[d][c] = act( (sum_{s in N(d) ∪ {d}} hs[s][c]) * dinv[d] + b[c] )
__global__ __launch_bounds__(256) void aggregate(
    const __half* __restrict__ hs, const int* __restrict__ rowptr,
    const int* __restrict__ srcs, const float* __restrict__ dinv,
    const float* __restrict__ b, float* __restrict__ out, int n, int do_relu)
{
    int wid  = (blockIdx.x * blockDim.x + threadIdx.x) >> 6;
    int lane = threadIdx.x & 63;
    if (wid >= n) return;
    const int g = lane >> 3;       // 0..7
    const int q = lane & 7;        // 0..7
    int beg = rowptr[wid], end = rowptr[wid + 1];
    float acc[8] = {};
    if (g == 0) acc_row(acc, hs, wid, q);          // self-loop (pre-scaled)
    for (int e = beg + g; e < end; e += 8)
        acc_row(acc, hs, srcs[e], q);
    #pragma unroll
    for (int j = 0; j < 8; ++j) {
        acc[j] += __shfl_xor(acc[j], 8);
        acc[j] += __shfl_xor(acc[j], 16);
        acc[j] += __shfl_xor(acc[j], 32);
    }
    if (g == 0) {
        float dd = dinv[wid];
        float o[8];
        #pragma unroll
        for (int j = 0; j < 8; ++j) {
            float v = acc[j] * dd + b[q * 8 + j];
            o[j] = do_relu ? fmaxf(v, 0.f) : v;
        }
        float4* po = (float4*)(out + (size_t)wid * DCH + q * 8);
        po[0] = make_float4(o[0], o[1], o[2], o[3]);
        po[1] = make_float4(o[4], o[5], o[6], o[7]);
    }
}

extern "C" void kernel_launch(void* const* d_in, const int* in_sizes, int n_in,
                              void* d_out, int out_size, void* d_ws, size_t ws_size,
                              hipStream_t stream) {
    const float* x  = (const float*)d_in[0];
    const int*   ei = (const int*)d_in[1];
    const float* W1 = (const float*)d_in[2];
    const float* b1 = (const float*)d_in[3];
    const float* W2 = (const float*)d_in[4];
    const float* b2 = (const float*)d_in[5];
    const float* W3 = (const float*)d_in[6];
    const float* b3 = (const float*)d_in[7];

    const int N = in_sizes[0] / DCH;
    const int E = in_sizes[1] / 2;
    const int* src = ei;
    const int* dst = ei + E;
    const int NB = (N + BROWS - 1) >> NBSHIFT;     // 391

    char* ws = (char*)d_ws;
    size_t off = 0;
    auto alloc = [&](size_t bytes) { void* p = ws + off; off = (off + bytes + 255) & ~(size_t)255; return p; };
    int*    counts = (int*)   alloc((size_t)MAXNB * 4);
    int*    bases  = (int*)   alloc((size_t)MAXNB * 4);
    int*    cursor = (int*)   alloc((size_t)MAXNB * 4);
    int*    rowptr = (int*)   alloc(((size_t)N + 1) * 4);
    int*    srcs   = (int*)   alloc((size_t)E * 4);
    float*  dinv   = (float*) alloc((size_t)N * 4);
    __half* hs     = (__half*)alloc((size_t)N * DCH * 2);
    float*  agg    = (float*) alloc((size_t)N * DCH * 4);
    unsigned int* tmp = (unsigned int*)hs;         // alias: tmp dead before first gemm writes hs
    float* out = (float*)d_out;

    const int T = 256;
    const int gAG  = (N * DCH + T - 1) / T;        // one 64-lane wave per node
    const int gGM  = (N + 63) / 64;                // one block per 64-row tile
    const int nchk = (E + CHUNK - 1) / CHUNK;

    // ---- CSR build (counting sort by dst) ----
    zero_i32<<<(NB + T - 1) / T, T, 0, stream>>>(counts, NB);
    bucket_hist<<<256, T, 0, stream>>>(dst, counts, E, NB);
    bucket_scan<<<1, MAXNB, 0, stream>>>(counts, bases, cursor, rowptr, NB, N, E);
    bucket_scatter<<<nchk, T, 0, stream>>>(src, dst, cursor, tmp, E, NB);
    bucket_to_csr<<<NB, BROWS, 0, stream>>>(tmp, bases, counts, rowptr, srcs, dinv, N);

    // ---- layer 1: x -> agg ----
    gemm64<<<gGM, T, 0, stream>>>(x, W1, dinv, hs, N);
    aggregate<<<gAG, T, 0, stream>>>(hs, rowptr, srcs, dinv, b1, agg, N, 1);

    // ---- layer 2: agg -> agg ----
    gemm64<<<gGM, T, 0, stream>>>(agg, W2, dinv, hs, N);
    aggregate<<<gAG, T, 0, stream>>>(hs, rowptr, srcs, dinv, b2, agg, N, 1);

    // ---- layer 3: agg -> d_out ----
    gemm64<<<gGM, T, 0, stream>>>(agg, W3, dinv, hs, N);
    aggregate<<<gAG, T, 0, stream>>>(hs, rowptr, srcs, dinv, b3, out, N, 0);
}

// Round 6
// 251.182 us; speedup vs baseline: 5.1715x; 1.3720x over previous
//
#include <hip/hip_runtime.h>
#include <hip/hip_fp16.h>

#define DCH 64
#define NBSHIFT 8
#define BROWS 256            // nodes per bucket = 1<<NBSHIFT
#define MAXNB 512
#define CAP 8192             // pass-C staging capacity (edges per bucket)
#define CHUNK 4096           // pass-B edges per block

__global__ void zero_i32(int* __restrict__ p, int n) {
    int i = blockIdx.x * blockDim.x + threadIdx.x;
    if (i < n) p[i] = 0;
}

// pass A: global bucket histogram via per-block LDS histograms
__global__ __launch_bounds__(256) void bucket_hist(const int* __restrict__ dst,
                                                   int* __restrict__ counts, int E, int NB) {
    __shared__ int hist[MAXNB];
    for (int i = threadIdx.x; i < NB; i += blockDim.x) hist[i] = 0;
    __syncthreads();
    for (int e = blockIdx.x * blockDim.x + threadIdx.x; e < E; e += gridDim.x * blockDim.x)
        atomicAdd(&hist[dst[e] >> NBSHIFT], 1);
    __syncthreads();
    for (int i = threadIdx.x; i < NB; i += blockDim.x) {
        int c = hist[i];
        if (c) atomicAdd(&counts[i], c);
    }
}

// scan bucket counts -> bases, init global cursors; also rowptr[N]=E
__global__ __launch_bounds__(MAXNB) void bucket_scan(const int* __restrict__ counts,
        int* __restrict__ bases, int* __restrict__ cursor, int* __restrict__ rowptr,
        int NB, int N, int E) {
    __shared__ int lds[MAXNB];
    int t = threadIdx.x;
    int v = (t < NB) ? counts[t] : 0;
    lds[t] = v;
    __syncthreads();
    for (int off = 1; off < MAXNB; off <<= 1) {
        int add = (t >= off) ? lds[t - off] : 0;
        __syncthreads();
        lds[t] += add;
        __syncthreads();
    }
    if (t < NB) { int b = lds[t] - v; bases[t] = b; cursor[t] = b; }
    if (t == 0) rowptr[N] = E;
}

// pass B: scatter edges into bucket-contiguous regions as packed (dstLow8<<24)|src
__global__ __launch_bounds__(256) void bucket_scatter(const int* __restrict__ src,
        const int* __restrict__ dst, int* __restrict__ cursor,
        unsigned int* __restrict__ tmp, int E, int NB) {
    __shared__ int hist[MAXNB];
    __shared__ int res[MAXNB];
    const int base_e = blockIdx.x * CHUNK;
    const int nloc = min(CHUNK, E - base_e);
    for (int i = threadIdx.x; i < NB; i += blockDim.x) hist[i] = 0;
    __syncthreads();
    for (int i = threadIdx.x; i < nloc; i += blockDim.x)
        atomicAdd(&hist[dst[base_e + i] >> NBSHIFT], 1);
    __syncthreads();
    for (int i = threadIdx.x; i < NB; i += blockDim.x) {
        int c = hist[i];
        res[i] = c ? atomicAdd(&cursor[i], c) : 0;
        hist[i] = 0;                       // reuse as local cursor
    }
    __syncthreads();
    for (int i = threadIdx.x; i < nloc; i += blockDim.x) {
        int d = dst[base_e + i];
        int b = d >> NBSHIFT;
        int r = atomicAdd(&hist[b], 1);
        unsigned int packed = ((unsigned int)(d & (BROWS - 1)) << 24) |
                              (unsigned int)src[base_e + i];
        tmp[res[b] + r] = packed;
    }
}

// pass C: one block per bucket -> rowptr, dinv, coalesced srcs
__global__ __launch_bounds__(BROWS) void bucket_to_csr(
        const unsigned int* __restrict__ tmp, const int* __restrict__ bases,
        const int* __restrict__ counts, int* __restrict__ rowptr,
        int* __restrict__ srcs, float* __restrict__ dinv, int N) {
    __shared__ int hist[BROWS];
    __shared__ int off[BROWS];
    __shared__ int cur[BROWS];
    __shared__ int stage[CAP];
    const int b = blockIdx.x;
    const int base = bases[b], count = counts[b];
    const int t = threadIdx.x;
    hist[t] = 0;
    __syncthreads();
    for (int i = t; i < count; i += BROWS)
        atomicAdd(&hist[tmp[base + i] >> 24], 1);
    __syncthreads();
    int v = hist[t];
    off[t] = v;
    __syncthreads();
    for (int o = 1; o < BROWS; o <<= 1) {
        int add = (t >= o) ? off[t - o] : 0;
        __syncthreads();
        off[t] += add;
        __syncthreads();
    }
    int excl = off[t] - v;
    cur[t] = excl;
    int node = (b << NBSHIFT) + t;
    if (node <= N) rowptr[node] = base + excl;     // node==N lands in last bucket -> rowptr[N]=E
    if (node < N)  dinv[node] = rsqrtf((float)v + 1.0f);
    __syncthreads();
    const bool st = (count <= CAP);
    for (int i = t; i < count; i += BROWS) {
        unsigned int p = tmp[base + i];
        int low = p >> 24;
        int s = (int)(p & 0xFFFFFFu);
        int pos = atomicAdd(&cur[low], 1);
        if (st) stage[pos] = s;
        else    srcs[base + pos] = s;              // overflow fallback (uncoalesced, rare)
    }
    __syncthreads();
    if (st)
        for (int i = t; i < count; i += BROWS) srcs[base + i] = stage[i];
}

// register-tiled Hs[r][c] = half( (A[64xK] * W[KxC]) * dinv[r] ); 64x64 tile, 4x4/thread
// launch_bounds(256,4): cap 128 VGPR -> 4 blocks/CU. float4 LDS staging, pad 68.
__global__ __launch_bounds__(256, 4) void gemm64(const float* __restrict__ A,
        const float* __restrict__ W, const float* __restrict__ dinv,
        __half* __restrict__ H, int nrows) {
    __shared__ float Wl[64 * 64];      // [k][c]
    __shared__ float Al[64 * 68];      // [r][k], pad 68: f4-aligned, bank-stride 4
    #pragma unroll
    for (int j = 0; j < 4; ++j) {
        int idx = (int)threadIdx.x + j * 256;          // 0..1023
        float4 w = ((const float4*)W)[idx];
        int k = idx >> 4, c = (idx & 15) * 4;
        *(float4*)&Wl[k * 64 + c] = w;
    }
    const int tx = threadIdx.x & 15;
    const int ty = threadIdx.x >> 4;
    const int c0 = tx * 4, r0 = ty * 4;
    const int ntiles = (nrows + 63) >> 6;
    for (int tile = blockIdx.x; tile < ntiles; tile += gridDim.x) {
        const int rowbase = tile << 6;
        const int rmax = min(64, nrows - rowbase);
        __syncthreads();
        #pragma unroll
        for (int j = 0; j < 4; ++j) {
            int idx = (int)threadIdx.x + j * 256;
            int r = idx >> 4, k = (idx & 15) * 4;
            float4 a = (r < rmax) ? *(const float4*)(A + (size_t)(rowbase + r) * 64 + k)
                                  : make_float4(0.f, 0.f, 0.f, 0.f);
            *(float4*)&Al[r * 68 + k] = a;
        }
        __syncthreads();
        float acc[4][4] = {};
        #pragma unroll 8
        for (int k = 0; k < 64; ++k) {
            float4 wv = *(const float4*)&Wl[k * 64 + c0];
            float a0 = Al[(r0 + 0) * 68 + k];
            float a1 = Al[(r0 + 1) * 68 + k];
            float a2 = Al[(r0 + 2) * 68 + k];
            float a3 = Al[(r0 + 3) * 68 + k];
            acc[0][0] += a0 * wv.x; acc[0][1] += a0 * wv.y; acc[0][2] += a0 * wv.z; acc[0][3] += a0 * wv.w;
            acc[1][0] += a1 * wv.x; acc[1][1] += a1 * wv.y; acc[1][2] += a1 * wv.z; acc[1][3] += a1 * wv.w;
            acc[2][0] += a2 * wv.x; acc[2][1] += a2 * wv.y; acc[2][2] += a2 * wv.z; acc[2][3] += a2 * wv.w;
            acc[3][0] += a3 * wv.x; acc[3][1] += a3 * wv.y; acc[3][2] += a3 * wv.z; acc[3][3] += a3 * wv.w;
        }
        #pragma unroll
        for (int i = 0; i < 4; ++i) {
            int r = r0 + i;
            if (r < rmax) {
                float s = dinv[rowbase + r];
                __half2* ph = (__half2*)(H + (size_t)(rowbase + r) * 64 + c0);
                ph[0] = __floats2half2_rn(acc[i][0] * s, acc[i][1] * s);
                ph[1] = __floats2half2_rn(acc[i][2] * s, acc[i][3] * s);
            }
        }
    }
}

__device__ __forceinline__ void acc_row(float acc[8], const __half* __restrict__ hs,
                                        int s, int q) {
    const float4 v = *(const float4*)((const char*)hs + ((size_t)s << 7) + (q << 4));
    const __half2* hp = (const __half2*)&v;
    #pragma unroll
    for (int j = 0; j < 4; ++j) {
        float2 f = __half22float2(hp[j]);
        acc[2 * j]     += f.x;
        acc[2 * j + 1] += f.y;
    }
}

// one wave per dst node. lane = g*8+q: g = edge subgroup (8 edges in flight),
// q = channel oct (half8 = 16B). hs rows pre-scaled by dinv[src], fp16.
// out[d][c] = act( (sum_{s in N(d) ∪ {d}} hs[s][c]) * dinv[d] + b[c] )
__global__ __launch_bounds__(256) void aggregate(
    const __half* __restrict__ hs, const int* __restrict__ rowptr,
    const int* __restrict__ srcs, const float* __restrict__ dinv,
    const float* __restrict__ b, float* __restrict__ out, int n, int do_relu)
{
    int wid  = (blockIdx.x * blockDim.x + threadIdx.x) >> 6;
    int lane = threadIdx.x & 63;
    if (wid >= n) return;
    const int g = lane >> 3;       // 0..7
    const int q = lane & 7;        // 0..7
    int beg = rowptr[wid], end = rowptr[wid + 1];
    float acc[8] = {};
    if (g == 0) acc_row(acc, hs, wid, q);          // self-loop (pre-scaled)
    for (int e = beg + g; e < end; e += 8)
        acc_row(acc, hs, srcs[e], q);
    #pragma unroll
    for (int j = 0; j < 8; ++j) {
        acc[j] += __shfl_xor(acc[j], 8);
        acc[j] += __shfl_xor(acc[j], 16);
        acc[j] += __shfl_xor(acc[j], 32);
    }
    if (g == 0) {
        float dd = dinv[wid];
        float o[8];
        #pragma unroll
        for (int j = 0; j < 8; ++j) {
            float v = acc[j] * dd + b[q * 8 + j];
            o[j] = do_relu ? fmaxf(v, 0.f) : v;
        }
        float4* po = (float4*)(out + (size_t)wid * DCH + q * 8);
        po[0] = make_float4(o[0], o[1], o[2], o[3]);
        po[1] = make_float4(o[4], o[5], o[6], o[7]);
    }
}

extern "C" void kernel_launch(void* const* d_in, const int* in_sizes, int n_in,
                              void* d_out, int out_size, void* d_ws, size_t ws_size,
                              hipStream_t stream) {
    const float* x  = (const float*)d_in[0];
    const int*   ei = (const int*)d_in[1];
    const float* W1 = (const float*)d_in[2];
    const float* b1 = (const float*)d_in[3];
    const float* W2 = (const float*)d_in[4];
    const float* b2 = (const float*)d_in[5];
    const float* W3 = (const float*)d_in[6];
    const float* b3 = (const float*)d_in[7];

    const int N = in_sizes[0] / DCH;
    const int E = in_sizes[1] / 2;
    const int* src = ei;
    const int* dst = ei + E;
    const int NB = (N + BROWS - 1) >> NBSHIFT;     // 391

    char* ws = (char*)d_ws;
    size_t off = 0;
    auto alloc = [&](size_t bytes) { void* p = ws + off; off = (off + bytes + 255) & ~(size_t)255; return p; };
    int*    counts = (int*)   alloc((size_t)MAXNB * 4);
    int*    bases  = (int*)   alloc((size_t)MAXNB * 4);
    int*    cursor = (int*)   alloc((size_t)MAXNB * 4);
    int*    rowptr = (int*)   alloc(((size_t)N + 1) * 4);
    int*    srcs   = (int*)   alloc((size_t)E * 4);
    float*  dinv   = (float*) alloc((size_t)N * 4);
    __half* hs     = (__half*)alloc((size_t)N * DCH * 2);
    float*  agg    = (float*) alloc((size_t)N * DCH * 4);
    unsigned int* tmp = (unsigned int*)hs;         // alias: tmp dead before first gemm writes hs
    float* out = (float*)d_out;

    const int T = 256;
    const int gAG  = (N * DCH + T - 1) / T;        // one 64-lane wave per node
    const int gGM  = (N + 63) / 64;                // one block per 64-row tile
    const int nchk = (E + CHUNK - 1) / CHUNK;

    // ---- CSR build (counting sort by dst) ----
    zero_i32<<<(NB + T - 1) / T, T, 0, stream>>>(counts, NB);
    bucket_hist<<<256, T, 0, stream>>>(dst, counts, E, NB);
    bucket_scan<<<1, MAXNB, 0, stream>>>(counts, bases, cursor, rowptr, NB, N, E);
    bucket_scatter<<<nchk, T, 0, stream>>>(src, dst, cursor, tmp, E, NB);
    bucket_to_csr<<<NB, BROWS, 0, stream>>>(tmp, bases, counts, rowptr, srcs, dinv, N);

    // ---- layer 1: x -> agg ----
    gemm64<<<gGM, T, 0, stream>>>(x, W1, dinv, hs, N);
    aggregate<<<gAG, T, 0, stream>>>(hs, rowptr, srcs, dinv, b1, agg, N, 1);

    // ---- layer 2: agg -> agg ----
    gemm64<<<gGM, T, 0, stream>>>(agg, W2, dinv, hs, N);
    aggregate<<<gAG, T, 0, stream>>>(hs, rowptr, srcs, dinv, b2, agg, N, 1);

    // ---- layer 3: agg -> d_out ----
    gemm64<<<gGM, T, 0, stream>>>(agg, W3, dinv, hs, N);
    aggregate<<<gAG, T, 0, stream>>>(hs, rowptr, srcs, dinv, b3, out, N, 0);
}